// Round 9
// baseline (5437.130 us; speedup 1.0000x reference)
//
#include <hip/hip_runtime.h>
#include <hip/hip_fp16.h>

typedef _Float16 f16;
typedef _Float16 f16x8 __attribute__((ext_vector_type(8)));
typedef float f32x16 __attribute__((ext_vector_type(16)));

#define T_N 512
#define DSTEPS 48
#define TOTSTEPS 560
#define NWG 64

// ---- ws layout (bytes) ----
#define OFF_WHHE 0ull
#define SZ_WHH   (4096ull*1024*2)          // 8 MB
#define OFF_WHHD (OFF_WHHE + SZ_WHH)
#define OFF_WIHE (OFF_WHHD + SZ_WHH)
#define SZ_WIH   (4096ull*64*2)            // 512 KB
#define OFF_WIHD (OFF_WIHE + SZ_WIH)
#define OFF_WFC  (OFF_WIHD + SZ_WIH)
#define SZ_WFC   (64ull*1024*2)            // 128 KB
#define OFF_XP   (OFF_WFC + SZ_WFC)
#define SZ_XP    (512ull*4096*2)           // 4 MB
#define OFF_Y0   (OFF_XP + SZ_XP)
#define SZ_Y0    (4096ull*2)
#define OFF_BE   (OFF_Y0 + SZ_Y0)
#define OFF_BD   (OFF_BE + 4096ull*4)
#define OFF_FLG  (OFF_BD + 4096ull*4)
#define SZ_FLG   (561ull*2*256)            // BYTE flags[t][g][w(64)][wave(4)]
#define OFF_H    ((OFF_FLG + SZ_FLG + 255ull) & ~255ull)
// h produced at step t: 65536 f16 at OFF_H + t*131072;
// group g at +g*32768 f16, group layout [w_src(64)][b(32)][u(16)]

// dynamic LDS: whh slice 131072 B + gates [2][64][33] f32 = 16896 B  -> 147968 B (R2-proven size)
#define LDS_BYTES (131072 + 16896)

// ============================ prologue: pack to fp16 fragment-linear ============================
__global__ void prologue(const float* __restrict__ x, const float* __restrict__ y0,
    const float* __restrict__ wihE, const float* __restrict__ whhE,
    const float* __restrict__ bihE, const float* __restrict__ bhhE,
    const float* __restrict__ wihD, const float* __restrict__ whhD,
    const float* __restrict__ bihD, const float* __restrict__ bhhD,
    const float* __restrict__ wfc, char* __restrict__ ws)
{
  const long long gid = (long long)blockIdx.x * 256 + threadIdx.x;
  const long long gsz = (long long)gridDim.x * 256;
  f16* whhEp = (f16*)(ws + OFF_WHHE);
  f16* whhDp = (f16*)(ws + OFF_WHHD);
  f16* wihEp = (f16*)(ws + OFF_WIHE);
  f16* wihDp = (f16*)(ws + OFF_WIHD);
  f16* wfcp  = (f16*)(ws + OFF_WFC);
  f16* xp    = (f16*)(ws + OFF_XP);
  f16* y0p   = (f16*)(ws + OFF_Y0);
  float* be  = (float*)(ws + OFF_BE);
  float* bd  = (float*)(ws + OFF_BD);

  // Whh packs: idx = w*65536 + ks*32768 + i*16384 + kk*512 + lane*8 + j
  for (long long idx = gid; idx < 4194304ll; idx += gsz) {
    int j = (int)idx & 7, l = (int)(idx >> 3) & 63, kk = (int)(idx >> 9) & 31;
    int i = (int)(idx >> 14) & 1, ks = (int)(idx >> 15) & 1, w = (int)(idx >> 16);
    int nl = i * 32 + (l & 31);
    int grow = (nl >> 4) * 1024 + w * 16 + (nl & 15);
    int k = ks * 512 + kk * 16 + ((l >> 5) << 3) + j;
    whhEp[idx] = (f16)whhE[(long long)grow * 1024 + k];
    whhDp[idx] = (f16)whhD[(long long)grow * 1024 + k];
  }
  // Wih packs: idx = w*4096 + ks*2048 + i*1024 + kx*512 + lane*8 + j
  for (long long idx = gid; idx < 262144ll; idx += gsz) {
    int j = (int)idx & 7, l = (int)(idx >> 3) & 63, kx = (int)(idx >> 9) & 1;
    int i = (int)(idx >> 10) & 1, ks = (int)(idx >> 11) & 1, w = (int)(idx >> 12);
    int nl = i * 32 + (l & 31);
    int grow = (nl >> 4) * 1024 + w * 16 + (nl & 15);
    int k = (ks * 2 + kx) * 16 + ((l >> 5) << 3) + j;
    wihEp[idx] = (f16)wihE[grow * 64 + k];
    wihDp[idx] = (f16)wihD[grow * 64 + k];
  }
  // Wfc pack: idx = ks*32768 + i*16384 + kk*512 + lane*8 + j
  for (long long idx = gid; idx < 65536ll; idx += gsz) {
    int j = (int)idx & 7, l = (int)(idx >> 3) & 63, kk = (int)(idx >> 9) & 31;
    int i = (int)(idx >> 14) & 1, ks = (int)(idx >> 15) & 1;
    int o = i * 32 + (l & 31);
    int k = ks * 512 + kk * 16 + ((l >> 5) << 3) + j;
    wfcp[idx] = (f16)wfc[o * 1024 + k];
  }
  // x pack: [t][kkx(4)][b(64)][16]
  for (long long idx = gid; idx < 2097152ll; idx += gsz) {
    int kw = (int)idx & 15, b = (int)(idx >> 4) & 63, kkx = (int)(idx >> 10) & 3, t = (int)(idx >> 12);
    xp[idx] = (f16)x[(long long)b * 32768 + t * 64 + kkx * 16 + kw];
  }
  // y0 pack: [kkx][b][16]
  for (long long idx = gid; idx < 4096ll; idx += gsz) {
    int kw = (int)idx & 15, b = (int)(idx >> 4) & 63, kkx = (int)(idx >> 10) & 3;
    y0p[idx] = (f16)y0[b * 64 + kkx * 16 + kw];
  }
  // combined biases
  for (long long idx = gid; idx < 4096ll; idx += gsz) {
    be[idx] = bihE[idx] + bhhE[idx];
    bd[idx] = bihD[idx] + bhhD[idx];
  }
  // flags need no init: poison 0xAA bytes != 0x01, producers store 0x01
}

// ============================ persistent LSTM kernel ============================
__device__ __forceinline__ float sigf(float x) { return 1.0f / (1.0f + __expf(-x)); }
__device__ __forceinline__ float tanhfast(float x) {
  x = fminf(fmaxf(x, -15.f), 15.f);
  float e = __expf(2.0f * x);
  return (e - 1.0f) / (e + 1.0f);
}

#define MFMA(a,b,c) __builtin_amdgcn_mfma_f32_32x32x16_f16((a),(b),(c),0,0,0)
// gates: [ks][n(64)][m(33 pad)] f32; writes conflict-free, cell reads <=4-way (minor)
#define LG(kv,n,m) lds_g[(kv)*2112 + (n)*33 + (m)]

__launch_bounds__(256, 1)
__global__ void lstm_persist(char* __restrict__ ws, float* __restrict__ out,
                             const float* __restrict__ bfc)
{
  const int w    = blockIdx.x;      // owns hidden units [w*16, w*16+16)
  const int tid  = threadIdx.x;
  const int lane = tid & 63;
  const int wave = tid >> 6;
  const int wn   = wave & 1;        // N-half (gate rows 0..31 / 32..63 local)
  const int ks   = wave >> 1;       // K-half (h units 0..511 / 512..1023)

  const f16* whhEp = (const f16*)(ws + OFF_WHHE) + (size_t)w * 65536;
  const f16* whhDp = (const f16*)(ws + OFF_WHHD) + (size_t)w * 65536;
  const f16* wihEp = (const f16*)(ws + OFF_WIHE) + (size_t)w * 4096;
  const f16* wihDp = (const f16*)(ws + OFF_WIHD) + (size_t)w * 4096;
  const f16* wfcp  = (const f16*)(ws + OFF_WFC);
  const f16* xp    = (const f16*)(ws + OFF_XP);
  const f16* y0p   = (const f16*)(ws + OFF_Y0);
  const float* be  = (const float*)(ws + OFF_BE);
  const float* bd  = (const float*)(ws + OFF_BD);
  unsigned char* flags = (unsigned char*)(ws + OFF_FLG);
  f16* hb          = (f16*)(ws + OFF_H);

  extern __shared__ char smem[];
  f16*   whh_lds = (f16*)smem;                 // 131072 B (verbatim fragment-linear slice)
  float* lds_g   = (float*)(smem + 131072);    // [2][64][33] f32

  // frag offsets
  const int aoff_h = (lane & 31) * 16 + (lane >> 5) * 8;  // h group block [b32][u16]
  const int boff   = lane * 8;
  const int bsel   = tid >> 3;        // batch-in-group (cell phase), 0..31
  const int u0     = (tid & 7) * 2;   // first of 2 owned unit-locals

  // bias in registers: [gate][j] for units u0,u0+1
  float bE[8], bD[8];
#pragma unroll
  for (int g4 = 0; g4 < 4; ++g4)
#pragma unroll
    for (int j = 0; j < 2; ++j) {
      bE[g4 * 2 + j] = be[g4 * 1024 + w * 16 + u0 + j];
      bD[g4 * 2 + j] = bd[g4 * 1024 + w * 16 + u0 + j];
    }

  // stage encoder Whh slice into LDS
  for (int i = tid; i < 8192; i += 256)
    *(f16x8*)(whh_lds + (size_t)i * 8) = *(const f16x8*)(whhEp + (size_t)i * 8);

  float cst[2][2] = {{0.f, 0.f}, {0.f, 0.f}};   // c-state per [group][j]
  __syncthreads();   // whh_lds staged

#pragma unroll 1
  for (int t = 0; t < TOTSTEPS; ++t) {
    const bool enc = (t < T_N);

    if (t == T_N) {   // swap to decoder Whh in LDS (once)
      __syncthreads();
      for (int i = tid; i < 8192; i += 256)
        *(f16x8*)(whh_lds + (size_t)i * 8) = *(const f16x8*)(whhDp + (size_t)i * 8);
      __syncthreads();
    }

    const f16* xblk = enc ? (xp + (size_t)t * 4096) : y0p;
    const f16* wihp = enc ? wihEp : wihDp;

#pragma unroll
    for (int g = 0; g < 2; ++g) {
      // x-projection operands (independent of h)
      const int aoffx = (g * 32 + (lane & 31)) * 16 + (lane >> 5) * 8;
      f16x8 xa0 = *(const f16x8*)(xblk + (ks * 2 + 0) * 1024 + aoffx);
      f16x8 xa1 = *(const f16x8*)(xblk + (ks * 2 + 1) * 1024 + aoffx);
      f16x8 wb0 = *(const f16x8*)(wihp + ks * 2048 + wn * 1024 + 0 * 512 + boff);
      f16x8 wb1 = *(const f16x8*)(wihp + ks * 2048 + wn * 1024 + 1 * 512 + boff);

      f32x16 acc;
#pragma unroll
      for (int i = 0; i < 16; ++i) acc[i] = 0.f;
      acc = MFMA(xa0, wb0, acc);
      acc = MFMA(xa1, wb1, acc);

      if (t > 0) {
        // barrier-paced poll: lane's u32 covers producer WG=lane's 4 wave byte-flags
        const unsigned* fl = (const unsigned*)(flags + ((size_t)t * 2 + g) * 256);
        int ok;
        do {
          unsigned v = __hip_atomic_load(fl + lane, __ATOMIC_RELAXED, __HIP_MEMORY_SCOPE_AGENT);
          ok = (v == 0x01010101u);
        } while (__syncthreads_and(ok) == 0);

        // burst-load this wave's K-half of group-g h(t-1): 32 x 16B in flight
        const f16* hblk = hb + (size_t)(t - 1) * 65536 + (size_t)g * 32768;
        f16x8 af[32];
#pragma unroll
        for (int kk = 0; kk < 32; ++kk)
          af[kk] = *(const f16x8*)(hblk + (size_t)(ks * 32 + kk) * 512 + aoff_h);
#pragma unroll
        for (int kk = 0; kk < 32; ++kk) {
          f16x8 b = *(const f16x8*)(whh_lds + (size_t)ks * 32768 + wn * 16384 + kk * 512 + boff);
          acc = MFMA(af[kk], b, acc);
        }
      } else {
        __syncthreads();   // t==0: separate this phase's LDS writes from prior phase's reads
      }

      // K-half partials -> gates LDS
      {
        const int n0 = wn * 32 + (lane & 31);
        const int mb = (lane >> 5) << 2;
#pragma unroll
        for (int r = 0; r < 16; ++r) {
          const int m = mb + (r & 3) + ((r >> 2) << 3);
          LG(ks, n0, m) = acc[r];
        }
      }
      __syncthreads();

      // cell update: thread -> (batch bsel, unit-locals u0,u0+1)
      union { unsigned u32; f16 h2[2]; } hu;
#pragma unroll
      for (int j = 0; j < 2; ++j) {
        const int u = u0 + j;
        float ig = LG(0, u, bsel)      + LG(1, u, bsel)      + (enc ? bE[j]     : bD[j]);
        float fg = LG(0, 16 + u, bsel) + LG(1, 16 + u, bsel) + (enc ? bE[2 + j] : bD[2 + j]);
        float gg = LG(0, 32 + u, bsel) + LG(1, 32 + u, bsel) + (enc ? bE[4 + j] : bD[4 + j]);
        float og = LG(0, 48 + u, bsel) + LG(1, 48 + u, bsel) + (enc ? bE[6 + j] : bD[6 + j]);
        float cn = sigf(fg) * cst[g][j] + sigf(ig) * tanhfast(gg);
        cst[g][j] = cn;
        hu.h2[j] = (f16)(sigf(og) * tanhfast(cn));
      }

      // write-through h slice (wave covers contiguous 256B), wave-local drain, byte flag
      {
        f16* dst = hb + (size_t)t * 65536 + (size_t)g * 32768 + (size_t)w * 512 + bsel * 16 + u0;
        unsigned long long addr = (unsigned long long)(size_t)dst;
        asm volatile("global_store_dword %0, %1, off sc0 sc1" : : "v"(addr), "v"(hu.u32) : "memory");
      }
      asm volatile("s_waitcnt vmcnt(0)" ::: "memory");
      if (lane == 0) {
        unsigned long long fa = (unsigned long long)(size_t)
            (flags + ((size_t)(t + 1) * 2 + g) * 256 + w * 4 + wave);
        unsigned one = 1u;
        asm volatile("global_store_byte %0, %1, off sc0 sc1" : : "v"(fa), "v"(one) : "memory");
      }
      // LDS WAR safety: next phase's gate writes happen only after its poll barrier,
      // which all waves reach after their cell reads of this phase.
    }
  }

  // ---- FC epilogue: WG w<48 computes out[:, w*64..+64) from h of step 512+w ----
  if (w < DSTEPS) {
    const int s = T_N + 1 + w;   // flag row of h produced at step 512+w
#pragma unroll
    for (int g = 0; g < 2; ++g) {
      {
        const unsigned* fl = (const unsigned*)(flags + ((size_t)s * 2 + g) * 256);
        int ok;
        do {
          unsigned v = __hip_atomic_load(fl + lane, __ATOMIC_RELAXED, __HIP_MEMORY_SCOPE_AGENT);
          ok = (v == 0x01010101u);
        } while (__syncthreads_and(ok) == 0);
      }
      const f16* hblk = hb + (size_t)(s - 1) * 65536 + (size_t)g * 32768;
      f16x8 af[32];
#pragma unroll
      for (int kk = 0; kk < 32; ++kk)
        af[kk] = *(const f16x8*)(hblk + (size_t)(ks * 32 + kk) * 512 + aoff_h);

      f32x16 acc;
#pragma unroll
      for (int i = 0; i < 16; ++i) acc[i] = 0.f;
#pragma unroll
      for (int kk = 0; kk < 32; ++kk) {
        f16x8 b = *(const f16x8*)(wfcp + (size_t)ks * 32768 + wn * 16384 + kk * 512 + boff);
        acc = MFMA(af[kk], b, acc);
      }
      {
        const int n0 = wn * 32 + (lane & 31);
        const int mb = (lane >> 5) << 2;
#pragma unroll
        for (int r = 0; r < 16; ++r) {
          const int m = mb + (r & 3) + ((r >> 2) << 3);
          LG(ks, n0, m) = acc[r];
        }
      }
      __syncthreads();
      // thread -> batch bsel, features f0..f0+7 (8 cols x 8 feats = all 64)
      const int f0 = (tid & 7) * 8;
      float of[8];
#pragma unroll
      for (int j = 0; j < 8; ++j) {
        const int f = f0 + j;
        of[j] = LG(0, f, bsel) + LG(1, f, bsel) + bfc[f];
      }
      float* op = out + (size_t)(g * 32 + bsel) * 3072 + w * 64 + f0;
      *(float4*)(op)     = make_float4(of[0], of[1], of[2], of[3]);
      *(float4*)(op + 4) = make_float4(of[4], of[5], of[6], of[7]);
      __syncthreads();   // protect gates LDS before next group's writes
    }
  }
}

// ============================ launch ============================
extern "C" void kernel_launch(void* const* d_in, const int* in_sizes, int n_in,
                              void* d_out, int out_size, void* d_ws, size_t ws_size,
                              hipStream_t stream) {
  const float* x    = (const float*)d_in[0];
  const float* y0   = (const float*)d_in[1];
  const float* wihE = (const float*)d_in[2];
  const float* whhE = (const float*)d_in[3];
  const float* bihE = (const float*)d_in[4];
  const float* bhhE = (const float*)d_in[5];
  const float* wihD = (const float*)d_in[6];
  const float* whhD = (const float*)d_in[7];
  const float* bihD = (const float*)d_in[8];
  const float* bhhD = (const float*)d_in[9];
  const float* wfc  = (const float*)d_in[10];
  const float* bfc  = (const float*)d_in[11];
  char* ws   = (char*)d_ws;
  float* out = (float*)d_out;

  // idempotent, called every launch (capture-safe per R5; size proven per R2)
  (void)hipFuncSetAttribute((const void*)lstm_persist,
                            hipFuncAttributeMaxDynamicSharedMemorySize, LDS_BYTES);

  prologue<<<256, 256, 0, stream>>>(x, y0, wihE, whhE, bihE, bhhE,
                                    wihD, whhD, bihD, bhhD, wfc, ws);
  lstm_persist<<<NWG, 256, LDS_BYTES, stream>>>(ws, out, bfc);
}